// Round 5
// baseline (202.500 us; speedup 1.0000x reference)
//
#include <hip/hip_runtime.h>
#include <cstddef>

#define B_SZ 16
#define HW 1024
#define CCH 512
#define K_LEN 256
#define N_HEADS 8
#define EPS 1e-5f

typedef __bf16 bf16;
typedef bf16 bf16x8 __attribute__((ext_vector_type(8)));
typedef bf16 bf16x4 __attribute__((ext_vector_type(4)));
typedef bf16 bf16x2 __attribute__((ext_vector_type(2)));
typedef float f32x4 __attribute__((ext_vector_type(4)));

// async global->LDS, 16B per lane; LDS dest is wave-uniform base + lane*16
__device__ __forceinline__ void gl_lds16(const bf16* g, bf16* l) {
    __builtin_amdgcn_global_load_lds(
        (const __attribute__((address_space(1))) void*)g,
        (__attribute__((address_space(3))) void*)l, 16, 0, 0);
}

// ---------------------------------------------------------------------------
// Transpose+cast img: [B][512][1024] f32 -> [B][1024][512] bf16
// ---------------------------------------------------------------------------
__global__ __launch_bounds__(256) void transpose_cast_img(
    const float* __restrict__ src, bf16* __restrict__ dst)
{
    const int b  = blockIdx.z;
    const int s0 = blockIdx.x * 64;
    const int c0 = blockIdx.y * 64;
    __shared__ bf16 T[64][72];
    const int tid = threadIdx.x;
    {
        const int r = tid >> 2, cs = (tid & 3) << 4;
        const float* sp = src + ((size_t)b * CCH + c0 + r) * HW + s0 + cs;
        #pragma unroll
        for (int i = 0; i < 4; ++i) {
            float4 f = *(const float4*)(sp + i * 4);
            T[r][cs + i*4 + 0] = (bf16)f.x;
            T[r][cs + i*4 + 1] = (bf16)f.y;
            T[r][cs + i*4 + 2] = (bf16)f.z;
            T[r][cs + i*4 + 3] = (bf16)f.w;
        }
    }
    __syncthreads();
    {
        const int ss = tid >> 2, ks = (tid & 3) << 4;
        bf16x8 a, b8;
        #pragma unroll
        for (int j = 0; j < 8; ++j) { a[j] = T[ks + j][ss]; b8[j] = T[ks + 8 + j][ss]; }
        bf16* dp = dst + ((size_t)b * HW + s0 + ss) * CCH + c0 + ks;
        *(bf16x8*)dp = a;
        *(bf16x8*)(dp + 8) = b8;
    }
}

// ---------------------------------------------------------------------------
// Transpose+cast weights: W[k][n] f32 -> Wt[n][k] bf16, packed [4][512][512]
// ---------------------------------------------------------------------------
__global__ __launch_bounds__(256) void transpose_cast_w(
    const float* __restrict__ Wq, const float* __restrict__ Wk,
    const float* __restrict__ Wv, const float* __restrict__ Wo,
    bf16* __restrict__ dst)
{
    const int w = blockIdx.z;
    const float* src = (w == 0) ? Wq : (w == 1) ? Wk : (w == 2) ? Wv : Wo;
    const int n0 = blockIdx.x * 64;
    const int k0 = blockIdx.y * 64;
    __shared__ bf16 T[64][72];
    const int tid = threadIdx.x;
    {
        const int r = tid >> 2, cs = (tid & 3) << 4;
        const float* sp = src + (size_t)(k0 + r) * CCH + n0 + cs;
        #pragma unroll
        for (int i = 0; i < 4; ++i) {
            float4 f = *(const float4*)(sp + i * 4);
            T[r][cs + i*4 + 0] = (bf16)f.x;
            T[r][cs + i*4 + 1] = (bf16)f.y;
            T[r][cs + i*4 + 2] = (bf16)f.z;
            T[r][cs + i*4 + 3] = (bf16)f.w;
        }
    }
    __syncthreads();
    {
        const int nn = tid >> 2, ks = (tid & 3) << 4;
        bf16x8 a, b8;
        #pragma unroll
        for (int j = 0; j < 8; ++j) { a[j] = T[ks + j][nn]; b8[j] = T[ks + 8 + j][nn]; }
        bf16* dp = dst + (size_t)w * CCH * CCH + (size_t)(n0 + nn) * CCH + k0 + ks;
        *(bf16x8*)dp = a;
        *(bf16x8*)(dp + 8) = b8;
    }
}

// ---------------------------------------------------------------------------
// Elementwise cast audio f32 -> bf16
// ---------------------------------------------------------------------------
__global__ __launch_bounds__(256) void cast_audio(
    const float* __restrict__ src, bf16* __restrict__ dst)
{
    const size_t i = ((size_t)blockIdx.x * 256 + threadIdx.x) * 8;
    float4 a = *(const float4*)(src + i);
    float4 b = *(const float4*)(src + i + 4);
    bf16x8 o;
    o[0] = (bf16)a.x; o[1] = (bf16)a.y; o[2] = (bf16)a.z; o[3] = (bf16)a.w;
    o[4] = (bf16)b.x; o[5] = (bf16)b.y; o[6] = (bf16)b.z; o[7] = (bf16)b.w;
    *(bf16x8*)(dst + i) = o;
}

// ---------------------------------------------------------------------------
// MFMA bf16 GEMM (m97-style): out[m][n] = sum_k A[m][k]*Bt[n][k] + bias[n]
// 128x128 tile, BK=32, global_load_lds staging. Ct orientation: lane&15 = m,
// quad*4+reg = n -> 8B bf16x4 stores. Used for Q projection.
// ---------------------------------------------------------------------------
__global__ __launch_bounds__(256) void gemm_bf16_mfma(
    const bf16* __restrict__ A, const bf16* __restrict__ Bt,
    const float* __restrict__ bias, bf16* __restrict__ out)
{
    const int tid  = threadIdx.x;
    const int wave = tid >> 6, lane = tid & 63;
    const int m0 = blockIdx.x * 128;
    const int n0 = blockIdx.y * 128;
    const int l15 = lane & 15, quad = lane >> 4;
    const int wm = (wave >> 1) * 64, wn = (wave & 1) * 64;

    __shared__ bf16 As[128 * 32];
    __shared__ bf16 Bs[128 * 32];

    const int r16 = lane >> 2;
    const int ks  = (lane & 3) * 8;

    f32x4 acc[4][4];
    #pragma unroll
    for (int i = 0; i < 4; ++i)
        #pragma unroll
        for (int j = 0; j < 4; ++j)
            acc[i][j] = (f32x4){0.f, 0.f, 0.f, 0.f};

    for (int k0 = 0; k0 < 512; k0 += 32) {
        #pragma unroll
        for (int i = 0; i < 2; ++i) {
            const int c = wave * 2 + i;
            gl_lds16(A  + (size_t)(m0 + c * 16 + r16) * 512 + k0 + ks, &As[c * 512]);
            gl_lds16(Bt + (size_t)(n0 + c * 16 + r16) * 512 + k0 + ks, &Bs[c * 512]);
        }
        __syncthreads();
        bf16x8 af[4], bfr[4];
        #pragma unroll
        for (int i = 0; i < 4; ++i)
            af[i] = *(const bf16x8*)&As[(wm + i * 16 + l15) * 32 + quad * 8];
        #pragma unroll
        for (int j = 0; j < 4; ++j)
            bfr[j] = *(const bf16x8*)&Bs[(wn + j * 16 + l15) * 32 + quad * 8];
        #pragma unroll
        for (int i = 0; i < 4; ++i)
            #pragma unroll
            for (int j = 0; j < 4; ++j)
                acc[i][j] = __builtin_amdgcn_mfma_f32_16x16x32_bf16(bfr[j], af[i], acc[i][j], 0, 0, 0);
        __syncthreads();
    }

    #pragma unroll
    for (int j = 0; j < 4; ++j) {
        const int gn = n0 + wn + j * 16 + quad * 4;
        const f32x4 bv4 = *(const f32x4*)(bias + gn);
        #pragma unroll
        for (int i = 0; i < 4; ++i) {
            const int gm = m0 + wm + i * 16 + l15;
            bf16x4 ov;
            #pragma unroll
            for (int r = 0; r < 4; ++r) ov[r] = (bf16)(acc[i][j][r] + bv4[r]);
            *(bf16x4*)(out + (size_t)gm * 512 + gn) = ov;
        }
    }
}

// ---------------------------------------------------------------------------
// KV GEMM: cols <512 -> K row-major kh[b][h][key][64]; cols >=512 -> V
// transposed vt[b][h][d][256].
// ---------------------------------------------------------------------------
__global__ __launch_bounds__(256) void gemm_kv_mfma(
    const bf16* __restrict__ A, const bf16* __restrict__ Bt,
    const float* __restrict__ bk, const float* __restrict__ bv,
    bf16* __restrict__ khout, bf16* __restrict__ vtout)
{
    const int tid  = threadIdx.x;
    const int wave = tid >> 6, lane = tid & 63;
    const int m0 = blockIdx.x * 128;
    const int n0 = blockIdx.y * 128;
    const int l15 = lane & 15, quad = lane >> 4;
    const int wm = (wave >> 1) * 64, wn = (wave & 1) * 64;

    __shared__ bf16 As[128 * 32];
    __shared__ bf16 Bs[128 * 32];

    const int r16 = lane >> 2;
    const int ks  = (lane & 3) * 8;

    f32x4 acc[4][4];
    #pragma unroll
    for (int i = 0; i < 4; ++i)
        #pragma unroll
        for (int j = 0; j < 4; ++j)
            acc[i][j] = (f32x4){0.f, 0.f, 0.f, 0.f};

    for (int k0 = 0; k0 < 512; k0 += 32) {
        #pragma unroll
        for (int i = 0; i < 2; ++i) {
            const int c = wave * 2 + i;
            gl_lds16(A  + (size_t)(m0 + c * 16 + r16) * 512 + k0 + ks, &As[c * 512]);
            gl_lds16(Bt + (size_t)(n0 + c * 16 + r16) * 512 + k0 + ks, &Bs[c * 512]);
        }
        __syncthreads();
        bf16x8 af[4], bfr[4];
        #pragma unroll
        for (int i = 0; i < 4; ++i)
            af[i] = *(const bf16x8*)&As[(wm + i * 16 + l15) * 32 + quad * 8];
        #pragma unroll
        for (int j = 0; j < 4; ++j)
            bfr[j] = *(const bf16x8*)&Bs[(wn + j * 16 + l15) * 32 + quad * 8];
        #pragma unroll
        for (int i = 0; i < 4; ++i)
            #pragma unroll
            for (int j = 0; j < 4; ++j)
                acc[i][j] = __builtin_amdgcn_mfma_f32_16x16x32_bf16(af[i], bfr[j], acc[i][j], 0, 0, 0);
        __syncthreads();
    }

    #pragma unroll
    for (int j = 0; j < 4; ++j) {
        const int gn = n0 + wn + j * 16 + l15;
        if (gn < 512) {
            const int h = gn >> 6, d = gn & 63;
            const float bias = bk[gn];
            #pragma unroll
            for (int i = 0; i < 4; ++i) {
                const int gm = m0 + wm + i * 16 + quad * 4;
                const int b = gm >> 8, key = gm & 255;
                bf16* base = khout + ((((size_t)b * N_HEADS + h) * K_LEN) + key) * 64 + d;
                #pragma unroll
                for (int r = 0; r < 4; ++r)
                    base[(size_t)r * 64] = (bf16)(acc[i][j][r] + bias);
            }
        } else {
            const int ch = gn - 512;
            const int h = ch >> 6, d = ch & 63;
            const float bias = bv[ch];
            #pragma unroll
            for (int i = 0; i < 4; ++i) {
                const int gm = m0 + wm + i * 16 + quad * 4;
                const int b = gm >> 8, key = gm & 255;
                bf16x4 pk;
                #pragma unroll
                for (int r = 0; r < 4; ++r) pk[r] = (bf16)(acc[i][j][r] + bias);
                *(bf16x4*)(vtout + (((size_t)b * N_HEADS + h) * 64 + d) * K_LEN + key) = pk;
            }
        }
    }
}

// ---------------------------------------------------------------------------
// MFMA attention (unchanged): S^T trick + exact softmax + Vt@Pt.
// ---------------------------------------------------------------------------
__global__ __launch_bounds__(256) void attn_mfma(
    const bf16* __restrict__ q,    // [B*1024][512]
    const bf16* __restrict__ kh,   // [B][H][256][64]
    const bf16* __restrict__ vt,   // [B][H][64][256]
    bf16* __restrict__ o)          // [B*1024][512]
{
    const int bh = blockIdx.x;
    const int s0 = blockIdx.y * 64;
    const int tid = threadIdx.x;
    const int wave = tid >> 6, lane = tid & 63;
    const int l15 = lane & 15, quad = lane >> 4;
    const int b = bh >> 3, h = bh & 7;

    __shared__ bf16 KsPt[18432];   // Ks [256][72]; later Pt: 4 waves x [16][264]
    __shared__ bf16 Vs[16896];     // Vt [64][264]

    const bf16* khb = kh + (size_t)bh * K_LEN * 64;
    const bf16* vtb = vt + (size_t)bh * 64 * K_LEN;

    #pragma unroll
    for (int i = 0; i < 8; ++i) {
        const int chunk = tid + (i << 8);
        const int key = chunk >> 3, dseg = (chunk & 7) << 3;
        *(bf16x8*)&KsPt[key * 72 + dseg] = *(const bf16x8*)(khb + key * 64 + dseg);
        const int d = chunk >> 5, kseg = (chunk & 31) << 3;
        *(bf16x8*)&Vs[d * 264 + kseg] = *(const bf16x8*)(vtb + d * 256 + kseg);
    }
    __syncthreads();

    const int qrow = s0 + wave * 16 + l15;
    const bf16* qp = q + ((size_t)(b * HW + qrow)) * 512 + h * 64 + quad * 8;
    const bf16x8 qf0 = *(const bf16x8*)qp;
    const bf16x8 qf1 = *(const bf16x8*)(qp + 32);

    f32x4 acc[16];
    #pragma unroll
    for (int m = 0; m < 16; ++m) acc[m] = (f32x4){0.f, 0.f, 0.f, 0.f};
    #pragma unroll
    for (int m = 0; m < 16; ++m) {
        const bf16x8 a0 = *(const bf16x8*)&KsPt[(m * 16 + l15) * 72 + quad * 8];
        const bf16x8 a1 = *(const bf16x8*)&KsPt[(m * 16 + l15) * 72 + 32 + quad * 8];
        acc[m] = __builtin_amdgcn_mfma_f32_16x16x32_bf16(a0, qf0, acc[m], 0, 0, 0);
        acc[m] = __builtin_amdgcn_mfma_f32_16x16x32_bf16(a1, qf1, acc[m], 0, 0, 0);
    }

    float mx = -1e30f;
    #pragma unroll
    for (int m = 0; m < 16; ++m)
        mx = fmaxf(mx, fmaxf(fmaxf(acc[m][0], acc[m][1]), fmaxf(acc[m][2], acc[m][3])));
    mx = fmaxf(mx, __shfl_xor(mx, 16, 64));
    mx = fmaxf(mx, __shfl_xor(mx, 32, 64));

    __syncthreads();

    bf16* PtW = &KsPt[wave * 4224];
    float l_sum = 0.f;
    #pragma unroll
    for (int m = 0; m < 16; ++m) {
        bf16x4 pk;
        #pragma unroll
        for (int r = 0; r < 4; ++r) {
            const float p = __expf((acc[m][r] - mx) * 0.125f);
            l_sum += p;
            pk[r] = (bf16)p;
        }
        *(bf16x4*)&PtW[l15 * 264 + m * 16 + quad * 4] = pk;
    }
    l_sum += __shfl_xor(l_sum, 16, 64);
    l_sum += __shfl_xor(l_sum, 32, 64);
    __syncthreads();

    f32x4 oacc[4];
    #pragma unroll
    for (int m = 0; m < 4; ++m) oacc[m] = (f32x4){0.f, 0.f, 0.f, 0.f};
    #pragma unroll
    for (int s = 0; s < 8; ++s) {
        const bf16x8 pb = *(const bf16x8*)&PtW[l15 * 264 + s * 32 + quad * 8];
        #pragma unroll
        for (int m = 0; m < 4; ++m) {
            const bf16x8 va = *(const bf16x8*)&Vs[(m * 16 + l15) * 264 + s * 32 + quad * 8];
            oacc[m] = __builtin_amdgcn_mfma_f32_16x16x32_bf16(va, pb, oacc[m], 0, 0, 0);
        }
    }

    const float inv = 1.0f / l_sum;
    bf16* op = o + ((size_t)(b * HW + qrow)) * 512 + h * 64 + quad * 4;
    #pragma unroll
    for (int m = 0; m < 4; ++m) {
        bf16x4 ov;
        #pragma unroll
        for (int r = 0; r < 4; ++r) ov[r] = (bf16)(oacc[m][r] * inv);
        *(bf16x4*)&op[m * 16] = ov;
    }
}

// ---------------------------------------------------------------------------
// Fused out-projection + bias + residual + LayerNorm + transpose.
// Block: 512 threads (8 waves), 64 m-rows x full N=512. Wave w owns n-chunk
// w*64 (64x64 tile, acc 4x4 f32x4, Ct orientation: lane&15=m, quad*4+reg=n).
// Epilogue: y = acc + bo + residual; row stats via shfl + LDS cross-wave;
// normalize; stage bf16 Ys[64][522] (strides chosen: writes 4B-aligned,
// transposed reads ~2-way banks = free); coalesced f32 stores to out[b][c][s].
// ---------------------------------------------------------------------------
__global__ __launch_bounds__(512) void gemm_oln(
    const bf16* __restrict__ A,      // attn out [B*1024][512]
    const bf16* __restrict__ Wt,     // Wo^T [512][512]
    const float* __restrict__ bo,
    const bf16* __restrict__ imgb,   // residual [B*1024][512]
    const float* __restrict__ gamma, const float* __restrict__ beta,
    float* __restrict__ out)         // [B][512][1024]
{
    const int tid  = threadIdx.x;
    const int wave = tid >> 6, lane = tid & 63;
    const int l15 = lane & 15, quad = lane >> 4;
    const int m0 = blockIdx.x * 64;
    const int b  = m0 >> 10, s0 = m0 & 1023;
    const int wn = wave * 64;

    __shared__ union {
        struct { bf16 As[64 * 32]; bf16 Bs[512 * 32]; } st;
        bf16 Ys[64 * 522];
    } u;
    __shared__ float rsumS[64 * 8];
    __shared__ float rsqS[64 * 8];

    const int r16 = lane >> 2;
    const int ks  = (lane & 3) * 8;

    f32x4 acc[4][4];
    #pragma unroll
    for (int i = 0; i < 4; ++i)
        #pragma unroll
        for (int j = 0; j < 4; ++j)
            acc[i][j] = (f32x4){0.f, 0.f, 0.f, 0.f};

    for (int k0 = 0; k0 < 512; k0 += 32) {
        // B: Wo^T full 512 rows, 32 chunks of 16 rows; 4 chunks per wave
        #pragma unroll
        for (int t = 0; t < 4; ++t) {
            const int cb = wave + (t << 3);
            gl_lds16(Wt + (size_t)(cb * 16 + r16) * 512 + k0 + ks, &u.st.Bs[cb * 512]);
        }
        // A: 4 chunks, waves 0..3
        if (wave < 4)
            gl_lds16(A + (size_t)(m0 + wave * 16 + r16) * 512 + k0 + ks, &u.st.As[wave * 512]);
        __syncthreads();
        bf16x8 af[4], bfr[4];
        #pragma unroll
        for (int i = 0; i < 4; ++i)
            af[i] = *(const bf16x8*)&u.st.As[(i * 16 + l15) * 32 + quad * 8];
        #pragma unroll
        for (int j = 0; j < 4; ++j)
            bfr[j] = *(const bf16x8*)&u.st.Bs[(wn + j * 16 + l15) * 32 + quad * 8];
        #pragma unroll
        for (int i = 0; i < 4; ++i)
            #pragma unroll
            for (int j = 0; j < 4; ++j)
                acc[i][j] = __builtin_amdgcn_mfma_f32_16x16x32_bf16(bfr[j], af[i], acc[i][j], 0, 0, 0);
        __syncthreads();
    }

    // bias + residual; per-row partial stats
    float rs_[4] = {0.f, 0.f, 0.f, 0.f};
    float rq_[4] = {0.f, 0.f, 0.f, 0.f};
    #pragma unroll
    for (int j = 0; j < 4; ++j) {
        const int n = wn + j * 16 + quad * 4;
        const f32x4 bo4 = *(const f32x4*)(bo + n);
        #pragma unroll
        for (int i = 0; i < 4; ++i) {
            const int lm = i * 16 + l15;
            const bf16x4 res = *(const bf16x4*)(imgb + (size_t)(m0 + lm) * 512 + n);
            #pragma unroll
            for (int r = 0; r < 4; ++r) {
                const float y = acc[i][j][r] + bo4[r] + (float)res[r];
                acc[i][j][r] = y;
                rs_[i] += y;
                rq_[i] += y * y;
            }
        }
    }
    #pragma unroll
    for (int i = 0; i < 4; ++i) {
        rs_[i] += __shfl_xor(rs_[i], 16, 64);
        rs_[i] += __shfl_xor(rs_[i], 32, 64);
        rq_[i] += __shfl_xor(rq_[i], 16, 64);
        rq_[i] += __shfl_xor(rq_[i], 32, 64);
    }
    if (quad == 0) {
        #pragma unroll
        for (int i = 0; i < 4; ++i) {
            rsumS[(i * 16 + l15) * 8 + wave] = rs_[i];
            rsqS[(i * 16 + l15) * 8 + wave]  = rq_[i];
        }
    }
    __syncthreads();

    float mu[4], rstd[4];
    #pragma unroll
    for (int i = 0; i < 4; ++i) {
        const int lm = i * 16 + l15;
        float s = 0.f, q = 0.f;
        #pragma unroll
        for (int w = 0; w < 8; ++w) { s += rsumS[lm * 8 + w]; q += rsqS[lm * 8 + w]; }
        mu[i] = s * (1.f / 512.f);
        rstd[i] = rsqrtf(q * (1.f / 512.f) - mu[i] * mu[i] + EPS);
    }

    // normalize -> Ys[64][522] bf16 (overlays As/Bs; safe after the k-loop's
    // final barrier + the stats barrier above)
    #pragma unroll
    for (int j = 0; j < 4; ++j) {
        const int n = wn + j * 16 + quad * 4;
        const f32x4 g4 = *(const f32x4*)(gamma + n);
        const f32x4 b4 = *(const f32x4*)(beta + n);
        #pragma unroll
        for (int i = 0; i < 4; ++i) {
            const int lm = i * 16 + l15;
            float z[4];
            #pragma unroll
            for (int r = 0; r < 4; ++r)
                z[r] = (acc[i][j][r] - mu[i]) * rstd[i] * g4[r] + b4[r];
            bf16x2 z01, z23;
            z01[0] = (bf16)z[0]; z01[1] = (bf16)z[1];
            z23[0] = (bf16)z[2]; z23[1] = (bf16)z[3];
            *(bf16x2*)&u.Ys[lm * 522 + n]     = z01;
            *(bf16x2*)&u.Ys[lm * 522 + n + 2] = z23;
        }
    }
    __syncthreads();

    // transposed coalesced write: wave w covers channels w*64..w*64+63
    float* ob = out + (size_t)b * CCH * HW + s0 + lane;
    #pragma unroll
    for (int it = 0; it < 32; ++it) {
        const int c = wn + it * 2;
        const bf16x2 z2 = *(const bf16x2*)&u.Ys[lane * 522 + c];
        ob[(size_t)c * HW]       = (float)z2[0];
        ob[(size_t)(c + 1) * HW] = (float)z2[1];
    }
}

// ---------------------------------------------------------------------------
extern "C" void kernel_launch(void* const* d_in, const int* in_sizes, int n_in,
                              void* d_out, int out_size, void* d_ws, size_t ws_size,
                              hipStream_t stream) {
    const float* img   = (const float*)d_in[0];
    const float* audio = (const float*)d_in[1];
    const float* Wq    = (const float*)d_in[2];
    const float* bq    = (const float*)d_in[3];
    const float* Wk    = (const float*)d_in[4];
    const float* bk    = (const float*)d_in[5];
    const float* Wv    = (const float*)d_in[6];
    const float* bv    = (const float*)d_in[7];
    const float* Wo    = (const float*)d_in[8];
    const float* bo    = (const float*)d_in[9];
    const float* gamma = (const float*)d_in[10];
    const float* beta  = (const float*)d_in[11];

    bf16* wsb    = (bf16*)d_ws;
    bf16* img_bf = wsb;                     // 8388608
    bf16* aud_bf = img_bf + 8388608;        // 2097152
    bf16* wT     = aud_bf + 2097152;        // 4*262144 (q,k,v,o)
    bf16* q_bf   = wT + 1048576;            // 8388608
    bf16* kh_bf  = q_bf + 8388608;          // 2097152  [B][H][256][64]
    bf16* vt_bf  = kh_bf + 2097152;         // 2097152  [B][H][64][256]
    bf16* a_bf   = vt_bf + 2097152;         // 8388608

    transpose_cast_img<<<dim3(16, 8, 16), 256, 0, stream>>>(img, img_bf);
    cast_audio<<<dim3(1024), 256, 0, stream>>>(audio, aud_bf);
    transpose_cast_w<<<dim3(8, 8, 4), 256, 0, stream>>>(Wq, Wk, Wv, Wo, wT);

    // Q projection: M=16384, N=512
    gemm_bf16_mfma<<<dim3(128, 4), 256, 0, stream>>>(img_bf, wT, bq, q_bf);
    // K|V fused: M=4096, N=1024
    gemm_kv_mfma<<<dim3(32, 8), 256, 0, stream>>>(aud_bf, wT + 262144, bk, bv, kh_bf, vt_bf);
    // MFMA attention
    attn_mfma<<<dim3(B_SZ * N_HEADS, HW / 64), 256, 0, stream>>>(q_bf, kh_bf, vt_bf, a_bf);
    // Fused out-projection + residual + LayerNorm + transpose
    gemm_oln<<<dim3(256), 512, 0, stream>>>(a_bf, wT + 3 * 262144, bo, img_bf, gamma, beta, (float*)d_out);
}